// Round 4
// baseline (237.862 us; speedup 1.0000x reference)
//
#include <hip/hip_runtime.h>

// NetVladCNN: B=64, D=512, H=W=32 (N=1024), K=64
// K1 : feat = w @ x[b] per (b, 128n-tile). x staged f32 via global_load_lds
//      (double-buffered); w A-frags read DIRECTLY from global (L1/L2-hot),
//      register-prefetched 1 iter ahead. feat f32 -> ws.
// K1b: softmax over H -> a bf16 (B,K,N)
// K2 : V = a @ x^T - 32*c per (b, 64d-tile). x staged via glds with granule
//      rotation (4-way-conflict b128 frags); a frags direct global bf16,
//      prefetched 1 ahead. Fused L2-normalize over k -> yw (B,K,D).
// K3 : transpose -> out (D,K,B)
// XCD swizzle: b = blk&63 so same-b blocks share one XCD's L2 (a reuse in K2).

typedef __attribute__((ext_vector_type(8))) short short8;
typedef __attribute__((ext_vector_type(4))) float f32x4;
typedef unsigned short u16;
typedef unsigned int u32;

union S8u { u32 q[4]; short8 s; };

__device__ __forceinline__ u32 pk2(float lo, float hi) {  // RNE bf16 pair pack
  union { float f; u32 u; } a, b; a.f = lo; b.f = hi;
  u32 xl = (a.u + 0x7fffu + ((a.u >> 16) & 1u)) >> 16;
  u32 xh = (b.u + 0x7fffu + ((b.u >> 16) & 1u)) & 0xffff0000u;
  return xl | xh;
}

__device__ __forceinline__ u16 bf1(float f) {
  union { float f; u32 u; } a; a.f = f;
  return (u16)((a.u + 0x7fffu + ((a.u >> 16) & 1u)) >> 16);
}

typedef const __attribute__((address_space(1))) u32 GU32;
typedef __attribute__((address_space(3))) u32 LU32;
__device__ __forceinline__ void glds16(const void* g, void* l) {
  __builtin_amdgcn_global_load_lds((GU32*)g, (LU32*)l, 16, 0, 0);
}

// ---------------- K1: features GEMM ----------------
// grid 512 = (ntile 8)*(b 64); block 256 = 4 waves; tile 64k x 128n, Kdim=512.
__global__ __launch_bounds__(256, 2) void k1_features(
    const float* __restrict__ x, const float* __restrict__ wgt,
    float* __restrict__ feat)
{
  const int blk = blockIdx.x;
  const int b = blk & 63, nt8 = blk >> 6;          // XCD = b%8
  const int nb = nt8 * 128;
  const int tid = threadIdx.x, lane = tid & 63, wv = tid >> 6;
  const int row = lane & 15, q = lane >> 4;

  __shared__ __align__(16) float xs[2][32][128];   // 32 KB

  const char* xbase = (const char*)(x + ((size_t)b << 19) + nb);
  const int dd0 = tid >> 5, cby = (tid & 31) * 16;
  const float* wrow = wgt + row * 512 + q * 8;     // + mt*16*512 + d0

  f32x4 acc[4][2];
#pragma unroll
  for (int mt = 0; mt < 4; mt++)
#pragma unroll
    for (int nt = 0; nt < 2; nt++) acc[mt][nt] = (f32x4){0.f, 0.f, 0.f, 0.f};

#define STAGE1(d0, buf)                                                        \
  {                                                                            \
    char* lx = (char*)&xs[buf][0][0];                                          \
    _Pragma("unroll")                                                          \
    for (int j = 0; j < 4; j++)                                                \
      glds16(xbase + (size_t)((d0) + j * 8 + dd0) * 4096 + cby,                \
             lx + j * 4096 + tid * 16);                                        \
  }

  STAGE1(0, 0);
  f32x4 wa[4][2];                                  // A prefetch (f32)
#pragma unroll
  for (int mt = 0; mt < 4; mt++) {
    wa[mt][0] = *(const f32x4*)(wrow + mt * 8192);
    wa[mt][1] = *(const f32x4*)(wrow + mt * 8192 + 4);
  }

  for (int i = 0; i < 16; i++) {
    const int buf = i & 1;
    __syncthreads();                               // drains glds + prefetch
    // pack current A from regs
    short8 af[4];
#pragma unroll
    for (int mt = 0; mt < 4; mt++) {
      S8u t;
      t.q[0] = pk2(wa[mt][0][0], wa[mt][0][1]); t.q[1] = pk2(wa[mt][0][2], wa[mt][0][3]);
      t.q[2] = pk2(wa[mt][1][0], wa[mt][1][1]); t.q[3] = pk2(wa[mt][1][2], wa[mt][1][3]);
      af[mt] = t.s;
    }
    if (i < 15) {
      STAGE1((i + 1) * 32, buf ^ 1);
      const float* wn = wrow + (i + 1) * 32;
#pragma unroll
      for (int mt = 0; mt < 4; mt++) {
        wa[mt][0] = *(const f32x4*)(wn + mt * 8192);
        wa[mt][1] = *(const f32x4*)(wn + mt * 8192 + 4);
      }
    }
    short8 bfv[2];
#pragma unroll
    for (int nt = 0; nt < 2; nt++) {
      const int n = wv * 32 + nt * 16 + row;
      const int d8 = q * 8;
      float v0 = xs[buf][d8 + 0][n], v1 = xs[buf][d8 + 1][n];
      float v2 = xs[buf][d8 + 2][n], v3 = xs[buf][d8 + 3][n];
      float v4 = xs[buf][d8 + 4][n], v5 = xs[buf][d8 + 5][n];
      float v6 = xs[buf][d8 + 6][n], v7 = xs[buf][d8 + 7][n];
      S8u t;
      t.q[0] = pk2(v0, v1); t.q[1] = pk2(v2, v3);
      t.q[2] = pk2(v4, v5); t.q[3] = pk2(v6, v7);
      bfv[nt] = t.s;
    }
#pragma unroll
    for (int nt = 0; nt < 2; nt++)
#pragma unroll
      for (int mt = 0; mt < 4; mt++)
        acc[mt][nt] = __builtin_amdgcn_mfma_f32_16x16x32_bf16(af[mt], bfv[nt], acc[mt][nt], 0, 0, 0);
  }
#undef STAGE1

  float* fb = feat + ((size_t)b << 16);
  const int nbw = nb + wv * 32;
#pragma unroll
  for (int mt = 0; mt < 4; mt++)
#pragma unroll
    for (int nt = 0; nt < 2; nt++)
#pragma unroll
      for (int r = 0; r < 4; r++)   // C layout: col=lane&15, row=q*4+r
        fb[(mt * 16 + q * 4 + r) * 1024 + nbw + nt * 16 + row] = acc[mt][nt][r];
}

// ---------------- K1b: softmax over H -> a bf16 (B,K,N) ----------------
__global__ __launch_bounds__(256) void k1b_softmax(
    const float* __restrict__ feat, u16* __restrict__ am)
{
  const int tid = threadIdx.x, lane = tid & 63, wv = tid >> 6;
  const int rid = blockIdx.x * 4 + wv;         // rid = b*64 + k
  const float* f = feat + ((size_t)rid << 10);
  u16* ar = am + ((size_t)rid << 10);
  const int w = lane & 31, half = lane >> 5;
  const int base = w + half * 512;
  float v[16];
  float m = -1e30f;
#pragma unroll
  for (int i = 0; i < 16; i++) { v[i] = f[base + i * 32]; m = fmaxf(m, v[i]); }
  m = fmaxf(m, __shfl_xor(m, 32));
  float s = 0.f;
#pragma unroll
  for (int i = 0; i < 16; i++) { v[i] = __expf(v[i] - m); s += v[i]; }
  s += __shfl_xor(s, 32);
  const float inv = 1.0f / s;
#pragma unroll
  for (int i = 0; i < 16; i++) ar[base + i * 32] = bf1(v[i] * inv);
}

// ---------------- K2: aggregation + fused normalize ----------------
// grid 512 = (dt 8)*(b 64); block 256 = 4 waves; wave: 64k x 16d; 32 n-iters.
// x staged via glds with granule rotation: LDS row r slot s (16B granules)
// holds floats ((s*4 + (r&3)*8) & 31); frag reads land 4-way-conflicted only.
__global__ __launch_bounds__(256, 2) void k2_aggregate(
    const float* __restrict__ x, const u16* __restrict__ am,
    const float* __restrict__ cc, float* __restrict__ yw)
{
  const int blk = blockIdx.x;
  const int b = blk & 63, dt = blk >> 6;           // XCD = b%8
  const int tid = threadIdx.x, lane = tid & 63, wv = tid >> 6;
  const int row = lane & 15, q = lane >> 4;

  __shared__ __align__(16) float xs[2][2048];      // 16 KB (64 rows x 32 n, rotated)

  const char* xbase = (const char*)(x + ((size_t)b << 19) + (size_t)dt * 64 * 1024);
  const u16* ab = am + ((size_t)b << 16) + row * 1024 + q * 8;  // + mt*16*1024 + n0
  // staging decomposition: granule f = j*256+tid; r=f>>3, s=f&7
  const int r0 = tid >> 3, s0g = tid & 7;

#define STAGE2(n0, buf)                                                        \
  {                                                                            \
    char* lxs = (char*)&xs[buf][0];                                            \
    _Pragma("unroll")                                                          \
    for (int j = 0; j < 2; j++) {                                              \
      const int r = j * 32 + r0;                                               \
      const int col = ((s0g * 4) + ((r & 3) << 3)) & 31;                       \
      glds16(xbase + (size_t)r * 4096 + (size_t)((n0) + col) * 4,              \
             lxs + (j * 256 + tid) * 16);                                      \
    }                                                                          \
  }

  f32x4 acc[4];
#pragma unroll
  for (int mt = 0; mt < 4; mt++) acc[mt] = (f32x4){0.f, 0.f, 0.f, 0.f};

  STAGE2(0, 0);
  short8 sa[4];                                    // a prefetch (bf16, no pack!)
#pragma unroll
  for (int mt = 0; mt < 4; mt++) sa[mt] = *(const short8*)(ab + mt * 16384);

  const int rB = wv * 16 + row;                    // frag d-row (block-local)
  const int slot = (2 * q - 2 * (rB & 3)) & 7;     // even; 32B contiguous
  const int fidx = rB * 32 + slot * 4;

  for (int i = 0; i < 32; i++) {
    const int buf = i & 1;
    __syncthreads();
    short8 af[4];
#pragma unroll
    for (int mt = 0; mt < 4; mt++) af[mt] = sa[mt];
    if (i < 31) {
      STAGE2((i + 1) * 32, buf ^ 1);
      const u16* an = ab + (i + 1) * 32;
#pragma unroll
      for (int mt = 0; mt < 4; mt++) sa[mt] = *(const short8*)(an + mt * 16384);
    }
    f32x4 g0 = *(const f32x4*)&xs[buf][fidx];
    f32x4 g1 = *(const f32x4*)&xs[buf][fidx + 4];
    S8u t;
    t.q[0] = pk2(g0[0], g0[1]); t.q[1] = pk2(g0[2], g0[3]);
    t.q[2] = pk2(g1[0], g1[1]); t.q[3] = pk2(g1[2], g1[3]);
    const short8 bfv = t.s;
#pragma unroll
    for (int mt = 0; mt < 4; mt++)
      acc[mt] = __builtin_amdgcn_mfma_f32_16x16x32_bf16(af[mt], bfv, acc[mt], 0, 0, 0);
  }
#undef STAGE2

  // epilogue: lane holds 16 k's for d = dcol; norm over k wave-local (quads)
  const int dcol = dt * 64 + wv * 16 + row;
  float v[16]; float ss = 0.f;
#pragma unroll
  for (int mt = 0; mt < 4; mt++)
#pragma unroll
    for (int r = 0; r < 4; r++) {
      const int k = mt * 16 + q * 4 + r;
      const float tv = acc[mt][r] - 32.0f * cc[k * 512 + dcol];  // Sum_n a = 32 exact
      v[mt * 4 + r] = tv; ss += tv * tv;
    }
  ss += __shfl_xor(ss, 16);
  ss += __shfl_xor(ss, 32);
  const float rn = 1.0f / fmaxf(sqrtf(ss), 1e-12f);  // 2nd normalize is identity
  float* yb = yw + ((size_t)b << 15) + dcol;
#pragma unroll
  for (int mt = 0; mt < 4; mt++)
#pragma unroll
    for (int r = 0; r < 4; r++)
      yb[(size_t)(mt * 16 + q * 4 + r) << 9] = v[mt * 4 + r] * rn;
}

// ---------------- K3: (B,K,D) -> (D,K,B) ----------------
__global__ __launch_bounds__(256) void k3_transpose(
    const float* __restrict__ yw, float* __restrict__ out)
{
  const int blk = blockIdx.x;
  const int k = blk & 63;
  const int dt = blk >> 6;
  const int d0 = dt * 64;
  const int tid = threadIdx.x;
  __shared__ float T[64][68];
  {
    const int bl = tid >> 2, seg = tid & 3;
    const float* src = yw + (size_t)bl * 32768 + k * 512 + d0 + seg * 16;
#pragma unroll
    for (int i = 0; i < 4; i++) {
      f32x4 v = *(const f32x4*)(src + i * 4);
#pragma unroll
      for (int jj = 0; jj < 4; jj++) T[seg * 16 + i * 4 + jj][bl] = v[jj];
    }
  }
  __syncthreads();
  {
    const int dl = tid >> 2, bseg = tid & 3;
    float* dst = out + (size_t)(d0 + dl) * 4096 + k * 64 + bseg * 16;
    const float* srcT = &T[dl][bseg * 16];
#pragma unroll
    for (int i = 0; i < 4; i++)
      *(f32x4*)(dst + i * 4) = *(const f32x4*)(srcT + i * 4);
  }
}

extern "C" void kernel_launch(void* const* d_in, const int* in_sizes, int n_in,
                              void* d_out, int out_size, void* d_ws, size_t ws_size,
                              hipStream_t stream) {
  const float* x = (const float*)d_in[0];
  const float* w = (const float*)d_in[1];
  const float* c = (const float*)d_in[2];
  float* out = (float*)d_out;
  char* ws = (char*)d_ws;
  float* feat = (float*)ws;                                  // 16.8 MiB f32 logits
  u16*   a_ws = (u16*)(ws + (size_t)17 * 1024 * 1024);       //  8.4 MiB bf16 a (B,K,N)
  float* yw   = (float*)(ws + (size_t)26 * 1024 * 1024);     //  8.4 MiB (B,K,D)
  k1_features <<<dim3(512),  dim3(256), 0, stream>>>(x, w, feat);
  k1b_softmax <<<dim3(1024), dim3(256), 0, stream>>>(feat, a_ws);
  k2_aggregate<<<dim3(512),  dim3(256), 0, stream>>>(x, a_ws, c, yw);
  k3_transpose<<<dim3(512),  dim3(256), 0, stream>>>(yw, out);
}